// Round 3
// baseline (1111.376 us; speedup 1.0000x reference)
//
#include <hip/hip_runtime.h>
#include <math.h>

#define B_  32768
#define K_  1024
#define N_  2048

typedef __bf16 bf16x8 __attribute__((ext_vector_type(8)));
typedef float  f32x4  __attribute__((ext_vector_type(4)));
typedef float  f4     __attribute__((ext_vector_type(4)));
typedef unsigned short us4 __attribute__((ext_vector_type(4)));

__device__ __forceinline__ unsigned short f2bf(float f) {
    unsigned u = __float_as_uint(f);
    u += 0x7fffu + ((u >> 16) & 1u);   // round-to-nearest-even
    return (unsigned short)(u >> 16);
}
__device__ __forceinline__ float bf2f(unsigned short s) {
    return __uint_as_float(((unsigned)s) << 16);
}
__device__ __forceinline__ float sigm(float x) { return 1.f / (1.f + __expf(-x)); }
__device__ __forceinline__ float tanh_fast(float x) { return 1.f - 2.f / (__expf(2.f * x) + 1.f); }

// ---------------- pack x || h -> XH bf16 [B, 1024] ----------------
__global__ __launch_bounds__(256) void cvt_xh_kernel(const float* __restrict__ x,
                                                     const float* __restrict__ h,
                                                     unsigned short* __restrict__ XH) {
    unsigned i = (blockIdx.x * 256u + threadIdx.x) * 4u;
    unsigned col = i & 1023u;
    unsigned row = i >> 10;
    const float* src = (col < 512u) ? (x + (size_t)row * 512u + col)
                                    : (h + (size_t)row * 512u + (col - 512u));
    f4 v = *(const f4*)src;
    us4 o;
    o.x = f2bf(v.x); o.y = f2bf(v.y); o.z = f2bf(v.z); o.w = f2bf(v.w);
    *(us4*)(XH + i) = o;
}

// ---------------- transpose-pack weights -> Wt bf16 [N=2048, K=1024] ----------------
// Strip-interleaved gate layout: row nrow = (j>>5)*128 + g*32 + (j&31);
// k<512 -> U_g[k][j], k>=512 -> V_g[k-512][j].
// A 128-row strip = all 4 gates of 32 consecutive j columns.
__global__ __launch_bounds__(256) void cvt_w_kernel(
    const float* __restrict__ Uf, const float* __restrict__ Vf,
    const float* __restrict__ Ui, const float* __restrict__ Vi,
    const float* __restrict__ Uo, const float* __restrict__ Vo,
    const float* __restrict__ Uc, const float* __restrict__ Vc,
    unsigned short* __restrict__ Wt) {
    __shared__ float tile[64][65];
    const float* srcs[8] = {Uf, Vf, Ui, Vi, Uo, Vo, Uc, Vc};
    const int w   = blockIdx.z;           // 0..7 : Uf,Vf,Ui,Vi,Uo,Vo,Uc,Vc
    const float* src = srcs[w];
    const int g   = w >> 1;
    const int isV = w & 1;
    const int j0  = blockIdx.x * 64;
    const int k0  = blockIdx.y * 64;
    const int t   = threadIdx.x;
    const int ty  = t >> 6, tx = t & 63;
    #pragma unroll
    for (int r = 0; r < 16; ++r) {
        int kl = ty * 16 + r;
        tile[kl][tx] = src[(size_t)(k0 + kl) * 512 + j0 + tx];   // coalesced over j
    }
    __syncthreads();
    #pragma unroll
    for (int r = 0; r < 16; ++r) {
        int jl = ty * 16 + r;
        int j  = j0 + jl;
        int nrow = ((j >> 5) << 7) + (g << 5) + (j & 31);
        Wt[(size_t)nrow * 1024 + isV * 512 + k0 + tx] = f2bf(tile[tx][jl]); // coalesced over k
    }
}

// ---------------- fused GEMM + LSTM cell ----------------
// 128x128 tile (128 batch rows x [32 j-cols x 4 gates]), BK=64, 4 waves each
// owning 32 rows x 128 cols (acc[2][8]), 16x16x32 bf16 MFMA.
// Wave's lane holds ALL FOUR gate pre-activations for its (row, j) in
// registers (nt = 2*g + hf), so the cell epilogue is lane-local and writes
// h_new/c_new as coalesced fp32 (both 64B halves of each 128B line from
// back-to-back stores). Depth-2 register prefetch; XCD swizzle keeps the
// 16 n-tiles of one m-tile on one XCD (Wt = 4MB resident in XCD L2).
__global__ __launch_bounds__(256, 2) void gemm_fused_kernel(
    const unsigned short* __restrict__ XH, const unsigned short* __restrict__ Wt,
    const float* __restrict__ cell,
    const float* __restrict__ bF, const float* __restrict__ bI,
    const float* __restrict__ bO, const float* __restrict__ bC,
    float* __restrict__ outH, float* __restrict__ outC) {
    __shared__ __attribute__((aligned(16))) unsigned short As[128 * 64];
    __shared__ __attribute__((aligned(16))) unsigned short Bs[128 * 64];
    const int t    = threadIdx.x;
    const int lane = t & 63;
    const int w    = t >> 6;

    const int bid = blockIdx.x;                 // 4096 blocks
    const int xcd = bid & 7;
    const int nb  = (bid >> 3) & 15;            // j-strip  (16)
    const int mb  = xcd * 32 + (bid >> 7);      // m-tile   (256); per-XCD: nb sweeps fastest
    const int m0  = mb * 128;
    const int n0  = nb * 128;                   // Wt strip row base
    const int j0  = nb * 32;                    // output column base

    f32x4 acc[2][8];
    #pragma unroll
    for (int i = 0; i < 2; ++i)
        #pragma unroll
        for (int j = 0; j < 8; ++j) { f32x4 z = {0.f, 0.f, 0.f, 0.f}; acc[i][j] = z; }

    // staging geometry: thread t fills LDS slots L = s*256+t (16B chunks);
    // slot r*8+cc holds global chunk cc^(r&7)  -> 2-way-only LDS aliasing
    size_t gOff[4];
    int    lOff[4];
    #pragma unroll
    for (int s = 0; s < 4; ++s) {
        int L  = s * 256 + t;
        int r  = L >> 3;
        int gc = (L & 7) ^ (r & 7);
        gOff[s] = (size_t)r * K_ + gc * 8;
        lOff[s] = L * 8;
    }
    const unsigned short* xb = XH + (size_t)m0 * K_;
    const unsigned short* wb = Wt + (size_t)n0 * K_;

    uint4 pa0[4], pb0[4], pa1[4], pb1[4];
    #pragma unroll
    for (int s = 0; s < 4; ++s) {
        pa0[s] = *(const uint4*)(xb + gOff[s]);
        pb0[s] = *(const uint4*)(wb + gOff[s]);
        pa1[s] = *(const uint4*)(xb + gOff[s] + 64);
        pb1[s] = *(const uint4*)(wb + gOff[s] + 64);
    }

#define MFMA_STAGE()                                                          \
    {                                                                         \
        _Pragma("unroll")                                                     \
        for (int ks = 0; ks < 2; ++ks) {                                      \
            const int c = ks * 4 + (lane >> 4);                               \
            bf16x8 af[2], bfr[8];                                             \
            _Pragma("unroll")                                                 \
            for (int mt = 0; mt < 2; ++mt) {                                  \
                int r = w * 32 + mt * 16 + (lane & 15);                       \
                int slot = r * 8 + (c ^ (r & 7));                             \
                af[mt] = *(const bf16x8*)(As + slot * 8);                     \
            }                                                                 \
            _Pragma("unroll")                                                 \
            for (int nt = 0; nt < 8; ++nt) {                                  \
                int r = nt * 16 + (lane & 15);                                \
                int slot = r * 8 + (c ^ (r & 7));                             \
                bfr[nt] = *(const bf16x8*)(Bs + slot * 8);                    \
            }                                                                 \
            _Pragma("unroll")                                                 \
            for (int mt = 0; mt < 2; ++mt)                                    \
                _Pragma("unroll")                                             \
                for (int nt = 0; nt < 8; ++nt)                                \
                    acc[mt][nt] = __builtin_amdgcn_mfma_f32_16x16x32_bf16(    \
                        af[mt], bfr[nt], acc[mt][nt], 0, 0, 0);               \
        }                                                                     \
    }

#define PHASE(PA, PB, KNEXT, VALID)                                           \
    __syncthreads();                                                          \
    _Pragma("unroll")                                                         \
    for (int s = 0; s < 4; ++s) {                                             \
        *(uint4*)(As + lOff[s]) = PA[s];                                      \
        *(uint4*)(Bs + lOff[s]) = PB[s];                                      \
    }                                                                         \
    __syncthreads();                                                          \
    if (VALID) {                                                              \
        _Pragma("unroll")                                                     \
        for (int s = 0; s < 4; ++s) {                                         \
            PA[s] = *(const uint4*)(xb + gOff[s] + (KNEXT));                  \
            PB[s] = *(const uint4*)(wb + gOff[s] + (KNEXT));                  \
        }                                                                     \
    }                                                                         \
    MFMA_STAGE();

    for (int itp = 0; itp < 8; ++itp) {
        PHASE(pa0, pb0, (2 * itp + 2) * 64, itp < 7);
        PHASE(pa1, pb1, (2 * itp + 3) * 64, itp < 7);
    }
#undef PHASE
#undef MFMA_STAGE

    // ---- fused LSTM cell epilogue (lane-local) ----
    // C/D layout: col n_local = nt*16 + (lane&15), row = w*32 + mt*16 + (lane>>4)*4 + reg
    // n_local -> gate g = nt>>1, jj = (nt&1)*16 + (lane&15)  =>  nt = 2g + hf
    const int lam   = lane & 15;
    const int rbase = m0 + w * 32 + ((lane >> 4) << 2);
    #pragma unroll
    for (int mt = 0; mt < 2; ++mt) {
        float hv[2][4], cv[2][4];
        #pragma unroll
        for (int hf = 0; hf < 2; ++hf) {
            const int j = j0 + hf * 16 + lam;
            const float bFv = bF[j], bIv = bI[j], bOv = bO[j], bCv = bC[j];
            const f32x4 pF = acc[mt][0 + hf];
            const f32x4 pI = acc[mt][2 + hf];
            const f32x4 pO = acc[mt][4 + hf];
            const f32x4 pC = acc[mt][6 + hf];
            #pragma unroll
            for (int rr = 0; rr < 4; ++rr) {
                const int row = rbase + mt * 16 + rr;
                const float cold = cell[(size_t)row * 512 + j];
                const float gf = sigm(pF[rr] + bFv);
                const float gi = sigm(pI[rr] + bIv);
                const float go = sigm(pO[rr] + bOv);
                const float ch = tanh_fast(pC[rr] + bCv);
                const float cn = gf * cold + gi * ch;
                hv[hf][rr] = go * tanh_fast(cn);
                cv[hf][rr] = cn;
            }
        }
        #pragma unroll
        for (int rr = 0; rr < 4; ++rr) {
            const int row = rbase + mt * 16 + rr;
            float* hp = outH + (size_t)row * 512 + j0 + lam;
            float* cp = outC + (size_t)row * 512 + j0 + lam;
            hp[0] = hv[0][rr]; hp[16] = hv[1][rr];   // both 64B halves of the 128B line
            cp[0] = cv[0][rr]; cp[16] = cv[1][rr];
        }
    }
}

// ---------------- logits + softmax over h_new ----------------
__global__ __launch_bounds__(256) void softmax_kernel(const float* __restrict__ hsrc,
                                                      const float* __restrict__ Wout,
                                                      const float* __restrict__ bout,
                                                      float* __restrict__ out) {
    const int lane = threadIdx.x & 63;
    const int row  = blockIdx.x * 4 + (threadIdx.x >> 6);
    const float* hr = hsrc + (size_t)row * 512;
    float p0 = 0.f, p1 = 0.f;
    #pragma unroll
    for (int half = 0; half < 2; ++half) {
        const int j = half * 256 + lane * 4;
        f4 hv = *(const f4*)(hr + j);
        f4 wa = *(const f4*)(Wout + j * 2);        // {w0[j],w1[j],w0[j+1],w1[j+1]}
        f4 wb = *(const f4*)(Wout + j * 2 + 4);
        p0 += hv.x * wa.x + hv.y * wa.z + hv.z * wb.x + hv.w * wb.z;
        p1 += hv.x * wa.y + hv.y * wa.w + hv.z * wb.y + hv.w * wb.w;
    }
    #pragma unroll
    for (int m = 32; m > 0; m >>= 1) {
        p0 += __shfl_xor(p0, m);
        p1 += __shfl_xor(p1, m);
    }
    if (lane == 0) {
        float l0 = p0 + bout[0];
        float l1 = p1 + bout[1];
        float mx = fmaxf(l0, l1);
        float e0 = __expf(l0 - mx), e1 = __expf(l1 - mx);
        float s  = e0 + e1;
        out[(size_t)row * 2 + 0] = e0 / s;
        out[(size_t)row * 2 + 1] = e1 / s;
    }
}

// ---------------- fallback (only if workspace is too small): naive fp32 ----------------
__global__ __launch_bounds__(256) void fallback_kernel(
    const float* __restrict__ x, const float* __restrict__ h, const float* __restrict__ cell,
    const float* __restrict__ Uf, const float* __restrict__ Vf, const float* __restrict__ bfp,
    const float* __restrict__ Ui, const float* __restrict__ Vi, const float* __restrict__ bip,
    const float* __restrict__ Uo, const float* __restrict__ Vo, const float* __restrict__ bop,
    const float* __restrict__ Uc, const float* __restrict__ Vc, const float* __restrict__ bcp,
    const float* __restrict__ Wout, const float* __restrict__ bout, float* __restrict__ out) {
    const int row = blockIdx.x;
    const int t   = threadIdx.x;
    __shared__ float xs[512], hs[512];
    xs[t]       = x[(size_t)row * 512 + t];
    xs[t + 256] = x[(size_t)row * 512 + t + 256];
    hs[t]       = h[(size_t)row * 512 + t];
    hs[t + 256] = h[(size_t)row * 512 + t + 256];
    __syncthreads();
    float p0 = 0.f, p1 = 0.f;
    for (int jj = 0; jj < 2; ++jj) {
        const int j = t + jj * 256;
        float af = bfp[j], ai = bip[j], ao = bop[j], ac = bcp[j];
        for (int k = 0; k < 512; ++k) {
            float xv = xs[k], hv = hs[k];
            af += xv * Uf[k * 512 + j] + hv * Vf[k * 512 + j];
            ai += xv * Ui[k * 512 + j] + hv * Vi[k * 512 + j];
            ao += xv * Uo[k * 512 + j] + hv * Vo[k * 512 + j];
            ac += xv * Uc[k * 512 + j] + hv * Vc[k * 512 + j];
        }
        float gf = 1.f / (1.f + __expf(-af));
        float gi = 1.f / (1.f + __expf(-ai));
        float go = 1.f / (1.f + __expf(-ao));
        float ch = tanhf(ac);
        float cold = cell[(size_t)row * 512 + j];
        float cn = gf * cold + gi * ch;
        float hn = go * tanhf(cn);
        out[65536 + (size_t)row * 512 + j]            = hn;
        out[65536 + 16777216 + (size_t)row * 512 + j] = cn;
        p0 += hn * Wout[j * 2 + 0];
        p1 += hn * Wout[j * 2 + 1];
    }
    #pragma unroll
    for (int off = 32; off > 0; off >>= 1) {
        p0 += __shfl_down(p0, off);
        p1 += __shfl_down(p1, off);
    }
    __shared__ float r0[4], r1[4];
    if ((t & 63) == 0) { r0[t >> 6] = p0; r1[t >> 6] = p1; }
    __syncthreads();
    if (t == 0) {
        float l0 = r0[0] + r0[1] + r0[2] + r0[3] + bout[0];
        float l1 = r1[0] + r1[1] + r1[2] + r1[3] + bout[1];
        float mx = fmaxf(l0, l1);
        float e0 = __expf(l0 - mx), e1 = __expf(l1 - mx);
        float s  = e0 + e1;
        out[(size_t)row * 2 + 0] = e0 / s;
        out[(size_t)row * 2 + 1] = e1 / s;
    }
}

extern "C" void kernel_launch(void* const* d_in, const int* in_sizes, int n_in,
                              void* d_out, int out_size, void* d_ws, size_t ws_size,
                              hipStream_t stream) {
    const float* x    = (const float*)d_in[0];
    const float* h    = (const float*)d_in[1];
    const float* c    = (const float*)d_in[2];
    const float* Uf   = (const float*)d_in[3];
    const float* Vf   = (const float*)d_in[4];
    const float* bfp  = (const float*)d_in[5];
    const float* Ui   = (const float*)d_in[6];
    const float* Vi   = (const float*)d_in[7];
    const float* bip  = (const float*)d_in[8];
    const float* Uo   = (const float*)d_in[9];
    const float* Vo   = (const float*)d_in[10];
    const float* bop  = (const float*)d_in[11];
    const float* Uc   = (const float*)d_in[12];
    const float* Vc   = (const float*)d_in[13];
    const float* bcp  = (const float*)d_in[14];
    const float* Wout = (const float*)d_in[15];
    const float* bout = (const float*)d_in[16];
    float* out = (float*)d_out;
    float* outH = out + 65536;
    float* outC = out + 65536 + 16777216;

    const size_t needXH = (size_t)B_ * K_ * 2;   // 64 MB
    const size_t needWt = (size_t)N_ * K_ * 2;   //  4 MB

    if (ws_size >= needXH + needWt) {
        unsigned short* XH = (unsigned short*)d_ws;
        unsigned short* Wt = (unsigned short*)((char*)d_ws + needXH);

        cvt_xh_kernel<<<(B_ * K_) / (256 * 4), 256, 0, stream>>>(x, h, XH);
        cvt_w_kernel<<<dim3(8, 8, 8), 256, 0, stream>>>(Uf, Vf, Ui, Vi, Uo, Vo, Uc, Vc, Wt);
        gemm_fused_kernel<<<4096, 256, 0, stream>>>(XH, Wt, c, bfp, bip, bop, bcp, outH, outC);
        softmax_kernel<<<B_ / 4, 256, 0, stream>>>(outH, Wout, bout, out);
    } else {
        fallback_kernel<<<B_, 256, 0, stream>>>(x, h, c, Uf, Vf, bfp, Ui, Vi, bip,
                                                Uo, Vo, bop, Uc, Vc, bcp, Wout, bout, out);
    }
}